// Round 4
// baseline (406.151 us; speedup 1.0000x reference)
//
#include <hip/hip_runtime.h>
#include <stdint.h>

#define D_MODEL 1024
#define NUM_HEADS 16
#define D_FF 4096
#define BB 2
#define TT 2048
#define NROWS (BB * TT)  // 4096

typedef __bf16 bf16x8 __attribute__((ext_vector_type(8)));
typedef short s16x8 __attribute__((ext_vector_type(8)));
typedef float f32x4 __attribute__((ext_vector_type(4)));

static __device__ __forceinline__ f32x4 mfma16(s16x8 a, s16x8 b, f32x4 c) {
  return __builtin_amdgcn_mfma_f32_16x16x32_bf16(
      __builtin_bit_cast(bf16x8, a), __builtin_bit_cast(bf16x8, b), c, 0, 0, 0);
}

// fp32 -> bf16 RNE
static __device__ __forceinline__ short f2b(float f) {
  union { float f; uint32_t u; } v; v.f = f;
  return (short)((v.u + 0x7FFFu + ((v.u >> 16) & 1u)) >> 16);
}

typedef __attribute__((address_space(1))) const unsigned int gu32;
typedef __attribute__((address_space(3))) unsigned int lu32;
static __device__ __forceinline__ void gload16(const short* g, short* l) {
  __builtin_amdgcn_global_load_lds((gu32*)g, (lu32*)l, 16, 0, 0);
}

// ---------------- RMSNorm: f32 [rows][1024] -> bf16 ----------------
__global__ __launch_bounds__(256) void rmsnorm_kernel(
    const float* __restrict__ x, const float* __restrict__ g, short* __restrict__ out) {
  const int row = blockIdx.x;
  const int tid = threadIdx.x;
  const float4 xv = *(const float4*)(x + (size_t)row * D_MODEL + tid * 4);
  float ss = xv.x * xv.x + xv.y * xv.y + xv.z * xv.z + xv.w * xv.w;
#pragma unroll
  for (int off = 32; off >= 1; off >>= 1) ss += __shfl_down(ss, off);
  __shared__ float part[4];
  if ((tid & 63) == 0) part[tid >> 6] = ss;
  __syncthreads();
  const float tot = part[0] + part[1] + part[2] + part[3];
  const float sc = rsqrtf(tot * (1.0f / D_MODEL) + 1e-5f);
  const float4 gv = *(const float4*)(g + tid * 4);
  short4 o;
  o.x = f2b(xv.x * sc * gv.x);
  o.y = f2b(xv.y * sc * gv.y);
  o.z = f2b(xv.z * sc * gv.z);
  o.w = f2b(xv.w * sc * gv.w);
  *(short4*)(out + (size_t)row * D_MODEL + tid * 4) = o;
}

// ---------------- f32 -> bf16 converts ----------------
__global__ __launch_bounds__(256) void cvt_kernel(
    const float* __restrict__ in, short* __restrict__ out, int n) {
  const int i = (blockIdx.x * 256 + threadIdx.x) * 8;
  if (i >= n) return;
  const float4 a = *(const float4*)(in + i);
  const float4 b = *(const float4*)(in + i + 4);
  union { short s[8]; s16x8 v; } u;
  u.s[0] = f2b(a.x); u.s[1] = f2b(a.y); u.s[2] = f2b(a.z); u.s[3] = f2b(a.w);
  u.s[4] = f2b(b.x); u.s[5] = f2b(b.y); u.s[6] = f2b(b.z); u.s[7] = f2b(b.w);
  *(s16x8*)(out + i) = u.v;
}

__global__ __launch_bounds__(256) void cvt4_kernel(
    const float* __restrict__ a, const float* __restrict__ b,
    const float* __restrict__ c, const float* __restrict__ d,
    short* __restrict__ oa, short* __restrict__ ob,
    short* __restrict__ oc, short* __restrict__ od) {
  const int gid = blockIdx.x * 256 + threadIdx.x;
  const int seg = gid >> 17;
  const int off = (gid & 131071) * 8;
  const float* in = seg == 0 ? a : seg == 1 ? b : seg == 2 ? c : d;
  short* out = seg == 0 ? oa : seg == 1 ? ob : seg == 2 ? oc : od;
  const float4 lo = *(const float4*)(in + off);
  const float4 hi = *(const float4*)(in + off + 4);
  union { short s[8]; s16x8 v; } u;
  u.s[0] = f2b(lo.x); u.s[1] = f2b(lo.y); u.s[2] = f2b(lo.z); u.s[3] = f2b(lo.w);
  u.s[4] = f2b(hi.x); u.s[5] = f2b(hi.y); u.s[6] = f2b(hi.z); u.s[7] = f2b(hi.w);
  *(s16x8*)(out + off) = u.v;
}

// ---------------- GEMM core: 2-phase double-buffered ----------------
// C[M,N] = A[M,K] @ B[N,K]^T, bf16, fp32 acc. BM = MFRAG*32, BN = 128.
// LDS chunk swizzle: slot = chunk ^ ((row>>1)&3)  (2-way residual = free).
template <int MFRAG>
__device__ __forceinline__ void gemm_core(
    const short* __restrict__ A, const short* __restrict__ Bw,
    int Ksl, int lda, int ldb, int brow, int bcol,
    short (&As)[2][MFRAG * 32][32], short (&Bs)[2][128][32],
    f32x4 (*acc)[4]) {
  const int tid = threadIdx.x;
  const int lane = tid & 63, wv = tid >> 6;
  const int l15 = lane & 15, lg = lane >> 4;
  const int wr = wv >> 1, wc = wv & 1;

  const int srow = wv * 16 + (lane >> 2);
  const int csrc = (lane & 3) ^ ((lane >> 3) & 3);  // pre-swizzled source chunk
  const int crd = (l15 >> 1) & 3;                   // read-side XOR
  const short* Ag[MFRAG / 2];
  const short* Bg[2];
#pragma unroll
  for (int j = 0; j < MFRAG / 2; ++j)
    Ag[j] = A + (size_t)(brow + j * 64 + srow) * lda + csrc * 8;
#pragma unroll
  for (int j = 0; j < 2; ++j)
    Bg[j] = Bw + (size_t)(bcol + j * 64 + srow) * ldb + csrc * 8;

  // prologue: stage tile 0 into buf 0
#pragma unroll
  for (int j = 0; j < MFRAG / 2; ++j)
    gload16(Ag[j], &As[0][0][0] + j * 2048 + wv * 512);
#pragma unroll
  for (int j = 0; j < 2; ++j)
    gload16(Bg[j], &Bs[0][0][0] + j * 2048 + wv * 512);

  int cur = 0;
  for (int k0 = 0; k0 < Ksl; k0 += 32) {
    __syncthreads();  // buf[cur] staged; prev reads of buf[cur^1] done
    if (k0 + 32 < Ksl) {
      const int nb = cur ^ 1, ko = k0 + 32;
#pragma unroll
      for (int j = 0; j < MFRAG / 2; ++j)
        gload16(Ag[j] + ko, &As[nb][0][0] + j * 2048 + wv * 512);
#pragma unroll
      for (int j = 0; j < 2; ++j)
        gload16(Bg[j] + ko, &Bs[nb][0][0] + j * 2048 + wv * 512);
    }
    s16x8 af[MFRAG], bfr[4];
#pragma unroll
    for (int m = 0; m < MFRAG; ++m)
      af[m] = *(const s16x8*)&As[cur][wr * (MFRAG * 16) + m * 16 + l15][(lg ^ crd) * 8];
#pragma unroll
    for (int n = 0; n < 4; ++n)
      bfr[n] = *(const s16x8*)&Bs[cur][wc * 64 + n * 16 + l15][(lg ^ crd) * 8];
#pragma unroll
    for (int m = 0; m < MFRAG; ++m)
#pragma unroll
      for (int n = 0; n < 4; ++n)
        acc[m][n] = mfma16(af[m], bfr[n], acc[m][n]);
    cur ^= 1;
  }
}

// MODE 0: bf16 C. MODE 2: f32 C + resid. MODE 3: bf16 gelu(C). MODE 4: f32 atomicAdd.
template <int MODE, int MFRAG>
__global__ __launch_bounds__(256) void gemm_bt(
    const short* __restrict__ A, const short* __restrict__ Bw,
    short* __restrict__ outb, float* __restrict__ outf,
    const float* __restrict__ resid, int Ksl, int lda, int N) {
  __shared__ __align__(16) short As[2][MFRAG * 32][32];
  __shared__ __align__(16) short Bs[2][128][32];
  f32x4 acc[MFRAG][4] = {};
  const int brow = blockIdx.y * (MFRAG * 32), bcol = blockIdx.x * 128;
  const int kz = blockIdx.z * Ksl;  // split-K slice offset
  gemm_core<MFRAG>(A + kz, Bw + kz, Ksl, lda, lda, brow, bcol, As, Bs, acc);

  const int tid = threadIdx.x, lane = tid & 63;
  const int wv = tid >> 6, wr = wv >> 1, wc = wv & 1;
  const int l15 = lane & 15, lg = lane >> 4;
#pragma unroll
  for (int m = 0; m < MFRAG; ++m)
#pragma unroll
    for (int n = 0; n < 4; ++n)
#pragma unroll
      for (int r = 0; r < 4; ++r) {
        const int grow = brow + wr * (MFRAG * 16) + m * 16 + lg * 4 + r;
        const int gcol = bcol + wc * 64 + n * 16 + l15;
        const float v = acc[m][n][r];
        const size_t idx = (size_t)grow * N + gcol;
        if (MODE == 0) {
          outb[idx] = f2b(v);
        } else if (MODE == 2) {
          outf[idx] = v + resid[idx];
        } else if (MODE == 3) {
          outb[idx] = f2b(0.5f * v * (1.0f + erff(v * 0.70710678118f)));
        } else {
          unsafeAtomicAdd(&outf[idx], v);
        }
      }
}

// Fused QKV. sel 0->Q (pre-scaled by 0.125*log2e for exp2 softmax), 1->K,
// 2->V (transposed [bh][d][t]).
__global__ __launch_bounds__(256) void gemm_qkv(
    const short* __restrict__ A, const short* __restrict__ Wq,
    const short* __restrict__ Wk, const short* __restrict__ Wv,
    short* __restrict__ qout, short* __restrict__ kout, short* __restrict__ vtout) {
  __shared__ __align__(16) short As[2][128][32];
  __shared__ __align__(16) short Bs[2][128][32];
  const int sel = blockIdx.x >> 3;
  const int bcol = (blockIdx.x & 7) * 128;
  const int brow = blockIdx.y * 128;
  const short* Bw = sel == 0 ? Wq : sel == 1 ? Wk : Wv;
  f32x4 acc[4][4] = {};
  gemm_core<4>(A, Bw, 1024, 1024, 1024, brow, bcol, As, Bs, acc);

  const int tid = threadIdx.x, lane = tid & 63;
  const int wv = tid >> 6, wr = wv >> 1, wc = wv & 1;
  const int l15 = lane & 15, lg = lane >> 4;
  short* outb = sel == 0 ? qout : kout;
#pragma unroll
  for (int m = 0; m < 4; ++m)
#pragma unroll
    for (int n = 0; n < 4; ++n)
#pragma unroll
      for (int r = 0; r < 4; ++r) {
        const int grow = brow + wr * 64 + m * 16 + lg * 4 + r;
        const int gcol = bcol + wc * 64 + n * 16 + l15;
        float v = acc[m][n][r];
        if (sel == 0) v *= 0.18033688011f;  // 0.125 * log2(e)
        const short vb = f2b(v);
        if (sel < 2) {
          outb[(size_t)grow * 1024 + gcol] = vb;
        } else {
          const int bq = grow >> 11, t = grow & 2047;
          const int hh = gcol >> 6, d = gcol & 63;
          vtout[(((size_t)((bq << 4) + hh) << 6) + d) * 2048 + t] = vb;
        }
      }
}

// ---------------- Flash-style causal attention, QBLK=128 KBLK=64 ----------
// 1-D grid of 512. Pairing remap: blocks i and i+256 (same CU under
// round-robin) carry qb pairs (15-k, k) -> uniform 36 k-tile units per CU,
// same bh (L2 reuse), bh % 8 = XCD.
__global__ __launch_bounds__(256) void attn_kernel(
    const short* __restrict__ qb_, const short* __restrict__ kb,
    const short* __restrict__ vt, short* __restrict__ att) {
  const int i = blockIdx.x;
  const int bh = i & 31, bq = bh >> 4, h = bh & 15;
  const int qtb = (i < 256) ? (15 - (i >> 5)) : ((i >> 5) - 8);
  const int qbase = qtb * 128;
  const int tid = threadIdx.x, lane = tid & 63, w = tid >> 6;
  const int l15 = lane & 15, lg = lane >> 4;

  __shared__ __align__(16) short Ks[2][64][64];
  __shared__ __align__(16) short Vs[2][64][64];
  __shared__ __align__(16) short Ps[4][32][64];

  const short* qhead = qb_ + (size_t)bq * 2048 * 1024 + h * 64;
  const short* khead = kb + (size_t)bq * 2048 * 1024 + h * 64;
  const short* vhead = vt + (size_t)bh * 64 * 2048;

  // Q fragments (pre-scaled by 0.125*log2e)
  s16x8 aq[2][2];
#pragma unroll
  for (int mq = 0; mq < 2; ++mq) {
    const short* qp = qhead + (size_t)(qbase + mq * 64 + w * 16 + l15) * 1024 + lg * 8;
    aq[mq][0] = *(const s16x8*)(qp);
    aq[mq][1] = *(const s16x8*)(qp + 32);
  }

  f32x4 acc[2][4] = {};
  float mrow[2][4], lrow[2][4];
#pragma unroll
  for (int mq = 0; mq < 2; ++mq)
#pragma unroll
    for (int r = 0; r < 4; ++r) { mrow[mq][r] = -1e30f; lrow[mq][r] = 0.f; }

  const int ssub = lane >> 3;
  const int gch = (lane & 7) ^ ssub;
  const int swz = l15 & 7;

  const int nkt = qbase / 64 + 2;

#define STAGE_KV(buf, k0)                                                     \
  {                                                                           \
    _Pragma("unroll") for (int j = 0; j < 2; ++j) {                           \
      const int row = j * 32 + w * 8 + ssub;                                  \
      gload16(khead + (size_t)((k0) + row) * 1024 + gch * 8,                  \
              &Ks[buf][0][0] + j * 2048 + w * 512);                           \
      gload16(vhead + (size_t)row * 2048 + (k0) + gch * 8,                    \
              &Vs[buf][0][0] + j * 2048 + w * 512);                           \
    }                                                                         \
  }

  STAGE_KV(0, 0);
  int cur = 0;
  for (int kt = 0; kt < nkt; ++kt) {
    const int k0 = kt * 64;
    __syncthreads();
    if (kt + 1 < nkt) STAGE_KV(cur ^ 1, k0 + 64);

    const bool act0 = (k0 <= qbase + w * 16 + 15);

    s16x8 bk[4][2];
#pragma unroll
    for (int c = 0; c < 4; ++c) {
      const int r = c * 16 + l15;
#pragma unroll
      for (int kh = 0; kh < 2; ++kh)
        bk[c][kh] = *(const s16x8*)&Ks[cur][r][((kh * 4 + lg) ^ swz) * 8];
    }

    f32x4 s[2][4] = {};
    __builtin_amdgcn_s_setprio(1);
#pragma unroll
    for (int mq = 0; mq < 2; ++mq) {
      if (mq == 0 && !act0) continue;
#pragma unroll
      for (int c = 0; c < 4; ++c) {
        s[mq][c] = mfma16(aq[mq][0], bk[c][0], s[mq][c]);
        s[mq][c] = mfma16(aq[mq][1], bk[c][1], s[mq][c]);
      }
    }
    __builtin_amdgcn_s_setprio(0);

    // mask + online softmax in log2 domain (defer-max THR=8)
#pragma unroll
    for (int mq = 0; mq < 2; ++mq) {
      if (mq == 0 && !act0) continue;
      const int rbase = qbase + mq * 64 + w * 16;
      if (k0 + 63 > rbase) {
#pragma unroll
        for (int c = 0; c < 4; ++c) {
          const int kcol = k0 + c * 16 + l15;
#pragma unroll
          for (int r = 0; r < 4; ++r)
            if (kcol > rbase + lg * 4 + r) s[mq][c][r] = -1e30f;
        }
      }
      float mt[4];
#pragma unroll
      for (int r = 0; r < 4; ++r)
        mt[r] = fmaxf(fmaxf(s[mq][0][r], s[mq][1][r]), fmaxf(s[mq][2][r], s[mq][3][r]));
#pragma unroll
      for (int off = 8; off >= 1; off >>= 1)
#pragma unroll
        for (int r = 0; r < 4; ++r) mt[r] = fmaxf(mt[r], __shfl_xor(mt[r], off));
      bool need = false;
#pragma unroll
      for (int r = 0; r < 4; ++r) need = need || (mt[r] > mrow[mq][r] + 8.0f);
      if (__any(need)) {
#pragma unroll
        for (int r = 0; r < 4; ++r) {
          const float mnew = fmaxf(mrow[mq][r], mt[r]);
          const float scl = exp2f(mrow[mq][r] - mnew);
          mrow[mq][r] = mnew;
          lrow[mq][r] *= scl;
#pragma unroll
          for (int df = 0; df < 4; ++df) acc[mq][df][r] *= scl;
        }
      }
#pragma unroll
      for (int c = 0; c < 4; ++c)
#pragma unroll
        for (int r = 0; r < 4; ++r) {
          const float p = exp2f(s[mq][c][r] - mrow[mq][r]);
          lrow[mq][r] += p;  // per-lane partial; cross-lane reduce deferred
          const int prow = mq * 16 + lg * 4 + r;
          const int ch = c * 2 + (l15 >> 3);
          Ps[w][prow][((ch ^ (prow & 7)) << 3) + (l15 & 7)] = f2b(p);
        }
    }

    s16x8 bv[4][2];
#pragma unroll
    for (int df = 0; df < 4; ++df) {
      const int r = df * 16 + l15;
#pragma unroll
      for (int kh = 0; kh < 2; ++kh)
        bv[df][kh] = *(const s16x8*)&Vs[cur][r][((kh * 4 + lg) ^ swz) * 8];
    }

    __builtin_amdgcn_s_setprio(1);
#pragma unroll
    for (int mq = 0; mq < 2; ++mq) {
      if (mq == 0 && !act0) continue;
#pragma unroll
      for (int kh = 0; kh < 2; ++kh) {
        const s16x8 pa = *(const s16x8*)&Ps[w][mq * 16 + l15][((kh * 4 + lg) ^ swz) * 8];
#pragma unroll
        for (int df = 0; df < 4; ++df)
          acc[mq][df] = mfma16(pa, bv[df][kh], acc[mq][df]);
      }
    }
    __builtin_amdgcn_s_setprio(0);
    cur ^= 1;
  }

#pragma unroll
  for (int mq = 0; mq < 2; ++mq) {
#pragma unroll
    for (int off = 8; off >= 1; off >>= 1)
#pragma unroll
      for (int r = 0; r < 4; ++r) lrow[mq][r] += __shfl_xor(lrow[mq][r], off);
    float inv[4];
#pragma unroll
    for (int r = 0; r < 4; ++r) inv[r] = 1.0f / lrow[mq][r];
#pragma unroll
    for (int df = 0; df < 4; ++df)
#pragma unroll
      for (int r = 0; r < 4; ++r) {
        const int qrow = qbase + mq * 64 + w * 16 + lg * 4 + r;
        const int d = df * 16 + l15;
        att[((size_t)(bq * 2048) + qrow) * 1024 + h * 64 + d] =
            f2b(acc[mq][df][r] * inv[r]);
      }
  }
}

// ---------------- launch ----------------
extern "C" void kernel_launch(void* const* d_in, const int* in_sizes, int n_in,
                              void* d_out, int out_size, void* d_ws, size_t ws_size,
                              hipStream_t stream) {
  const float* x  = (const float*)d_in[0];
  const float* wq = (const float*)d_in[1];
  const float* wk = (const float*)d_in[2];
  const float* wv = (const float*)d_in[3];
  const float* wo = (const float*)d_in[4];
  const float* w1 = (const float*)d_in[5];
  const float* w2 = (const float*)d_in[6];
  const float* g1 = (const float*)d_in[7];
  const float* g2 = (const float*)d_in[8];
  float* out = (float*)d_out;

  char* ws = (char*)d_ws;
  const size_t MB = 1u << 20;
  short* wq_b  = (short*)(ws + 0 * MB);
  short* wk_b  = (short*)(ws + 2 * MB);
  short* wv_b  = (short*)(ws + 4 * MB);
  short* wo_b  = (short*)(ws + 6 * MB);
  short* w1_b  = (short*)(ws + 8 * MB);
  short* w2_b  = (short*)(ws + 16 * MB);
  short* xn_b  = (short*)(ws + 24 * MB);
  short* q_b   = (short*)(ws + 32 * MB);
  short* k_b   = (short*)(ws + 40 * MB);
  short* vt_b  = (short*)(ws + 48 * MB);
  short* att_b = (short*)(ws + 56 * MB);
  short* gel_b = (short*)(ws + 32 * MB);  // aliases q/k/vt/att (dead by FFN1)

  // 1. xn = rmsnorm(x, g1)
  rmsnorm_kernel<<<NROWS, 256, 0, stream>>>(x, g1, xn_b);
  // 2. weights -> bf16
  cvt4_kernel<<<2048, 256, 0, stream>>>(wq, wk, wv, wo, wq_b, wk_b, wv_b, wo_b);
  cvt_kernel<<<2048, 256, 0, stream>>>(w1, w1_b, 1 << 22);
  cvt_kernel<<<2048, 256, 0, stream>>>(w2, w2_b, 1 << 22);
  // 3. fused QKV (Q pre-scaled for exp2, V transposed)
  gemm_qkv<<<dim3(24, 32), 256, 0, stream>>>(xn_b, wq_b, wk_b, wv_b, q_b, k_b, vt_b);
  // 4. attention (paired 1-D grid)
  attn_kernel<<<512, 256, 0, stream>>>(q_b, k_b, vt_b, att_b);
  // 5. x1 = x + att @ wo^T  (x1 in d_out, f32)
  gemm_bt<2, 2><<<dim3(8, 64), 256, 0, stream>>>(att_b, wo_b, nullptr, out, x, 1024, 1024, 1024);
  // 6. h = rmsnorm(x1, g2)
  rmsnorm_kernel<<<NROWS, 256, 0, stream>>>(out, g2, xn_b);
  // 7. g = gelu(h @ w1^T)
  gemm_bt<3, 4><<<dim3(32, 32), 256, 0, stream>>>(xn_b, w1_b, gel_b, nullptr, nullptr, 1024, 1024, 4096);
  // 8. out = x1 + g @ w2^T (split-K x2, atomic f32 onto x1)
  gemm_bt<4, 4><<<dim3(8, 32, 2), 256, 0, stream>>>(gel_b, w2_b, nullptr, out, nullptr, 2048, 4096, 1024);
}

// Round 5
// 369.625 us; speedup vs baseline: 1.0988x; 1.0988x over previous
//
#include <hip/hip_runtime.h>
#include <stdint.h>

#define D_MODEL 1024
#define NUM_HEADS 16
#define D_FF 4096
#define BB 2
#define TT 2048
#define NROWS (BB * TT)  // 4096

typedef __bf16 bf16x8 __attribute__((ext_vector_type(8)));
typedef short s16x8 __attribute__((ext_vector_type(8)));
typedef float f32x4 __attribute__((ext_vector_type(4)));

static __device__ __forceinline__ f32x4 mfma16(s16x8 a, s16x8 b, f32x4 c) {
  return __builtin_amdgcn_mfma_f32_16x16x32_bf16(
      __builtin_bit_cast(bf16x8, a), __builtin_bit_cast(bf16x8, b), c, 0, 0, 0);
}

// fp32 -> bf16 RNE
static __device__ __forceinline__ short f2b(float f) {
  union { float f; uint32_t u; } v; v.f = f;
  return (short)((v.u + 0x7FFFu + ((v.u >> 16) & 1u)) >> 16);
}

// two fp32 -> packed bf16x2 (low = a, high = b)
static __device__ __forceinline__ uint32_t pk2b(float a, float b) {
  uint32_t r;
  asm("v_cvt_pk_bf16_f32 %0, %1, %2" : "=v"(r) : "v"(a), "v"(b));
  return r;
}

typedef __attribute__((address_space(1))) const unsigned int gu32;
typedef __attribute__((address_space(3))) unsigned int lu32;
static __device__ __forceinline__ void gload16(const short* g, short* l) {
  __builtin_amdgcn_global_load_lds((gu32*)g, (lu32*)l, 16, 0, 0);
}

// ---------------- RMSNorm: f32 [rows][1024] -> bf16 ----------------
__global__ __launch_bounds__(256) void rmsnorm_kernel(
    const float* __restrict__ x, const float* __restrict__ g, short* __restrict__ out) {
  const int row = blockIdx.x;
  const int tid = threadIdx.x;
  const float4 xv = *(const float4*)(x + (size_t)row * D_MODEL + tid * 4);
  float ss = xv.x * xv.x + xv.y * xv.y + xv.z * xv.z + xv.w * xv.w;
#pragma unroll
  for (int off = 32; off >= 1; off >>= 1) ss += __shfl_down(ss, off);
  __shared__ float part[4];
  if ((tid & 63) == 0) part[tid >> 6] = ss;
  __syncthreads();
  const float tot = part[0] + part[1] + part[2] + part[3];
  const float sc = rsqrtf(tot * (1.0f / D_MODEL) + 1e-5f);
  const float4 gv = *(const float4*)(g + tid * 4);
  short4 o;
  o.x = f2b(xv.x * sc * gv.x);
  o.y = f2b(xv.y * sc * gv.y);
  o.z = f2b(xv.z * sc * gv.z);
  o.w = f2b(xv.w * sc * gv.w);
  *(short4*)(out + (size_t)row * D_MODEL + tid * 4) = o;
}

// ---------------- f32 -> bf16 converts ----------------
__global__ __launch_bounds__(256) void cvt_kernel(
    const float* __restrict__ in, short* __restrict__ out, int n) {
  const int i = (blockIdx.x * 256 + threadIdx.x) * 8;
  if (i >= n) return;
  const float4 a = *(const float4*)(in + i);
  const float4 b = *(const float4*)(in + i + 4);
  union { short s[8]; s16x8 v; } u;
  u.s[0] = f2b(a.x); u.s[1] = f2b(a.y); u.s[2] = f2b(a.z); u.s[3] = f2b(a.w);
  u.s[4] = f2b(b.x); u.s[5] = f2b(b.y); u.s[6] = f2b(b.z); u.s[7] = f2b(b.w);
  *(s16x8*)(out + i) = u.v;
}

__global__ __launch_bounds__(256) void cvt4_kernel(
    const float* __restrict__ a, const float* __restrict__ b,
    const float* __restrict__ c, const float* __restrict__ d,
    short* __restrict__ oa, short* __restrict__ ob,
    short* __restrict__ oc, short* __restrict__ od) {
  const int gid = blockIdx.x * 256 + threadIdx.x;
  const int seg = gid >> 17;
  const int off = (gid & 131071) * 8;
  const float* in = seg == 0 ? a : seg == 1 ? b : seg == 2 ? c : d;
  short* out = seg == 0 ? oa : seg == 1 ? ob : seg == 2 ? oc : od;
  const float4 lo = *(const float4*)(in + off);
  const float4 hi = *(const float4*)(in + off + 4);
  union { short s[8]; s16x8 v; } u;
  u.s[0] = f2b(lo.x); u.s[1] = f2b(lo.y); u.s[2] = f2b(lo.z); u.s[3] = f2b(lo.w);
  u.s[4] = f2b(hi.x); u.s[5] = f2b(hi.y); u.s[6] = f2b(hi.z); u.s[7] = f2b(hi.w);
  *(s16x8*)(out + off) = u.v;
}

// ---------------- GEMM core: 2-phase double-buffered ----------------
// C[M,N] = A[M,K] @ B[N,K]^T, bf16, fp32 acc. BM = MFRAG*32, BN = 128.
// LDS chunk swizzle: slot = chunk ^ ((row>>1)&3)  (2-way residual = free).
template <int MFRAG>
__device__ __forceinline__ void gemm_core(
    const short* __restrict__ A, const short* __restrict__ Bw,
    int Ksl, int lda, int ldb, int brow, int bcol,
    short (&As)[2][MFRAG * 32][32], short (&Bs)[2][128][32],
    f32x4 (*acc)[4]) {
  const int tid = threadIdx.x;
  const int lane = tid & 63, wv = tid >> 6;
  const int l15 = lane & 15, lg = lane >> 4;
  const int wr = wv >> 1, wc = wv & 1;

  const int srow = wv * 16 + (lane >> 2);
  const int csrc = (lane & 3) ^ ((lane >> 3) & 3);  // pre-swizzled source chunk
  const int crd = (l15 >> 1) & 3;                   // read-side XOR
  const short* Ag[MFRAG / 2];
  const short* Bg[2];
#pragma unroll
  for (int j = 0; j < MFRAG / 2; ++j)
    Ag[j] = A + (size_t)(brow + j * 64 + srow) * lda + csrc * 8;
#pragma unroll
  for (int j = 0; j < 2; ++j)
    Bg[j] = Bw + (size_t)(bcol + j * 64 + srow) * ldb + csrc * 8;

  // prologue: stage tile 0 into buf 0
#pragma unroll
  for (int j = 0; j < MFRAG / 2; ++j)
    gload16(Ag[j], &As[0][0][0] + j * 2048 + wv * 512);
#pragma unroll
  for (int j = 0; j < 2; ++j)
    gload16(Bg[j], &Bs[0][0][0] + j * 2048 + wv * 512);

  int cur = 0;
  for (int k0 = 0; k0 < Ksl; k0 += 32) {
    __syncthreads();  // buf[cur] staged; prev reads of buf[cur^1] done
    if (k0 + 32 < Ksl) {
      const int nb = cur ^ 1, ko = k0 + 32;
#pragma unroll
      for (int j = 0; j < MFRAG / 2; ++j)
        gload16(Ag[j] + ko, &As[nb][0][0] + j * 2048 + wv * 512);
#pragma unroll
      for (int j = 0; j < 2; ++j)
        gload16(Bg[j] + ko, &Bs[nb][0][0] + j * 2048 + wv * 512);
    }
    s16x8 af[MFRAG], bfr[4];
#pragma unroll
    for (int m = 0; m < MFRAG; ++m)
      af[m] = *(const s16x8*)&As[cur][wr * (MFRAG * 16) + m * 16 + l15][(lg ^ crd) * 8];
#pragma unroll
    for (int n = 0; n < 4; ++n)
      bfr[n] = *(const s16x8*)&Bs[cur][wc * 64 + n * 16 + l15][(lg ^ crd) * 8];
#pragma unroll
    for (int m = 0; m < MFRAG; ++m)
#pragma unroll
      for (int n = 0; n < 4; ++n)
        acc[m][n] = mfma16(af[m], bfr[n], acc[m][n]);
    cur ^= 1;
  }
}

// MODE 0: bf16 C. MODE 2: f32 C + resid. MODE 3: bf16 gelu(C). MODE 4: f32 atomicAdd.
template <int MODE, int MFRAG>
__global__ __launch_bounds__(256) void gemm_bt(
    const short* __restrict__ A, const short* __restrict__ Bw,
    short* __restrict__ outb, float* __restrict__ outf,
    const float* __restrict__ resid, int Ksl, int lda, int N) {
  __shared__ __align__(16) short As[2][MFRAG * 32][32];
  __shared__ __align__(16) short Bs[2][128][32];
  f32x4 acc[MFRAG][4] = {};
  const int brow = blockIdx.y * (MFRAG * 32), bcol = blockIdx.x * 128;
  const int kz = blockIdx.z * Ksl;  // split-K slice offset
  gemm_core<MFRAG>(A + kz, Bw + kz, Ksl, lda, lda, brow, bcol, As, Bs, acc);

  const int tid = threadIdx.x, lane = tid & 63;
  const int wv = tid >> 6, wr = wv >> 1, wc = wv & 1;
  const int l15 = lane & 15, lg = lane >> 4;
#pragma unroll
  for (int m = 0; m < MFRAG; ++m)
#pragma unroll
    for (int n = 0; n < 4; ++n)
#pragma unroll
      for (int r = 0; r < 4; ++r) {
        const int grow = brow + wr * (MFRAG * 16) + m * 16 + lg * 4 + r;
        const int gcol = bcol + wc * 64 + n * 16 + l15;
        const float v = acc[m][n][r];
        const size_t idx = (size_t)grow * N + gcol;
        if (MODE == 0) {
          outb[idx] = f2b(v);
        } else if (MODE == 2) {
          outf[idx] = v + resid[idx];
        } else if (MODE == 3) {
          outb[idx] = f2b(0.5f * v * (1.0f + erff(v * 0.70710678118f)));
        } else {
          unsafeAtomicAdd(&outf[idx], v);
        }
      }
}

// Fused QKV. sel 0->Q (pre-scaled by 0.125*log2e for exp2 softmax), 1->K,
// 2->V (transposed [bh][d][t]).
__global__ __launch_bounds__(256) void gemm_qkv(
    const short* __restrict__ A, const short* __restrict__ Wq,
    const short* __restrict__ Wk, const short* __restrict__ Wv,
    short* __restrict__ qout, short* __restrict__ kout, short* __restrict__ vtout) {
  __shared__ __align__(16) short As[2][128][32];
  __shared__ __align__(16) short Bs[2][128][32];
  const int sel = blockIdx.x >> 3;
  const int bcol = (blockIdx.x & 7) * 128;
  const int brow = blockIdx.y * 128;
  const short* Bw = sel == 0 ? Wq : sel == 1 ? Wk : Wv;
  f32x4 acc[4][4] = {};
  gemm_core<4>(A, Bw, 1024, 1024, 1024, brow, bcol, As, Bs, acc);

  const int tid = threadIdx.x, lane = tid & 63;
  const int wv = tid >> 6, wr = wv >> 1, wc = wv & 1;
  const int l15 = lane & 15, lg = lane >> 4;
  short* outb = sel == 0 ? qout : kout;
#pragma unroll
  for (int m = 0; m < 4; ++m)
#pragma unroll
    for (int n = 0; n < 4; ++n)
#pragma unroll
      for (int r = 0; r < 4; ++r) {
        const int grow = brow + wr * 64 + m * 16 + lg * 4 + r;
        const int gcol = bcol + wc * 64 + n * 16 + l15;
        float v = acc[m][n][r];
        if (sel == 0) v *= 0.18033688011f;  // 0.125 * log2(e)
        const short vb = f2b(v);
        if (sel < 2) {
          outb[(size_t)grow * 1024 + gcol] = vb;
        } else {
          const int bq = grow >> 11, t = grow & 2047;
          const int hh = gcol >> 6, d = gcol & 63;
          vtout[(((size_t)((bq << 4) + hh) << 6) + d) * 2048 + t] = vb;
        }
      }
}

// ---------------- Flash attention: swapped QK^T, 8 waves, QBLK=128 --------
// S^T = mfma(K, Q): lane holds 16 k-values for q = l15 -> in-lane softmax,
// P packed via v_cvt_pk_bf16_f32 into per-wave P^T [q][k] (granule-swizzled),
// PV A-frag = contiguous ds_read_b128. Wave w owns q-rows wqbase..wqbase+15.
__global__ __launch_bounds__(512) void attn_kernel(
    const short* __restrict__ qb_, const short* __restrict__ kb,
    const short* __restrict__ vt, short* __restrict__ att) {
  const int bh = blockIdx.x, bq = bh >> 4, h = bh & 15;
  const int qtb = (int)gridDim.y - 1 - (int)blockIdx.y;  // heavy first
  const int qbase = qtb * 128;
  const int tid = threadIdx.x, lane = tid & 63, w = tid >> 6;  // w in 0..7
  const int l15 = lane & 15, lg = lane >> 4;

  __shared__ __align__(16) short Ks[2][64][64];   // [k][d], granule-swizzled
  __shared__ __align__(16) short Vs[2][64][64];   // [d][k], granule-swizzled
  __shared__ __align__(16) short PsT[8][16][64];  // per-wave P^T [q][k], swz

  const short* qhead = qb_ + (size_t)bq * 2048 * 1024 + h * 64;
  const short* khead = kb + (size_t)bq * 2048 * 1024 + h * 64;
  const short* vhead = vt + (size_t)bh * 64 * 2048;

  const int wqbase = qbase + w * 16;
  const int qg = wqbase + l15;  // this lane's q-row (for softmax state)

  // Q B-frag (pre-scaled by 0.125*log2e): row=q=l15, k-dim = d
  s16x8 aq0, aq1;
  {
    const short* qp = qhead + (size_t)qg * 1024 + lg * 8;
    aq0 = *(const s16x8*)(qp);
    aq1 = *(const s16x8*)(qp + 32);
  }

  f32x4 acc[4] = {};           // [df]: q = wqbase+lg*4+r, d = df*16+l15
  float mrow = -1e30f, lrow = 0.f;  // per-lane, q = qg

  // staging: 512 threads x 16B = 8KB = one 64x64 bf16 tile per issue
  const int srow = lane >> 3;                 // + w*8
  const int gch = (lane & 7) ^ srow;          // pre-swizzled source chunk
  const int swz = l15 & 7;                    // read-side XOR

  const int nkt = qbase / 64 + 2;

#define STAGE_KV8(buf, k0)                                                    \
  {                                                                           \
    gload16(khead + (size_t)((k0) + w * 8 + srow) * 1024 + gch * 8,           \
            &Ks[buf][0][0] + w * 512);                                        \
    gload16(vhead + (size_t)(w * 8 + srow) * 2048 + (k0) + gch * 8,           \
            &Vs[buf][0][0] + w * 512);                                        \
  }

  STAGE_KV8(0, 0);
  int cur = 0;
  for (int kt = 0; kt < nkt; ++kt) {
    const int k0 = kt * 64;
    __syncthreads();  // buf[cur] staged; prev reads of buf[cur^1] done
    if (kt + 1 < nkt) STAGE_KV8(cur ^ 1, k0 + 64);

    const bool act = (k0 <= wqbase + 15);
    if (act) {
      // K A-frags: row k = c*16+l15, d-chunk kh*4+lg
      s16x8 bk[4][2];
#pragma unroll
      for (int c = 0; c < 4; ++c)
#pragma unroll
        for (int kh = 0; kh < 2; ++kh)
          bk[c][kh] = *(const s16x8*)&Ks[cur][c * 16 + l15][((kh * 4 + lg) ^ swz) * 8];

      // S^T = K Q^T : s[c][r] = S[k = k0+c*16+lg*4+r][q = qg]
      f32x4 s[4] = {};
      __builtin_amdgcn_s_setprio(1);
#pragma unroll
      for (int c = 0; c < 4; ++c) {
        s[c] = mfma16(bk[c][0], aq0, s[c]);
        s[c] = mfma16(bk[c][1], aq1, s[c]);
      }
      __builtin_amdgcn_s_setprio(0);

      // causal mask (only near diagonal)
      if (k0 + 63 > wqbase) {
#pragma unroll
        for (int c = 0; c < 4; ++c) {
          const int kgb = k0 + c * 16 + lg * 4;
#pragma unroll
          for (int r = 0; r < 4; ++r)
            if (kgb + r > qg) s[c][r] = -1e30f;
        }
      }

      // in-lane max over 16 values + cross-lg reduce (2 shuffles)
      float mt = s[0][0];
#pragma unroll
      for (int c = 0; c < 4; ++c)
#pragma unroll
        for (int r = 0; r < 4; ++r) mt = fmaxf(mt, s[c][r]);
      mt = fmaxf(mt, __shfl_xor(mt, 16));
      mt = fmaxf(mt, __shfl_xor(mt, 32));

      // defer-max (THR=8)
      if (__any(mt > mrow + 8.0f)) {
        const float mnew = fmaxf(mrow, mt);
        const float scl = exp2f(mrow - mnew);
        mrow = mnew;
        lrow *= scl;
        float sclT[4];
#pragma unroll
        for (int r = 0; r < 4; ++r)
          sclT[r] = __shfl(scl, (lane & 48) + lg * 4 + r);
#pragma unroll
        for (int df = 0; df < 4; ++df)
#pragma unroll
          for (int r = 0; r < 4; ++r) acc[df][r] *= sclT[r];
      }

      // P = exp2(S - m), pack pairs, store P^T quads (b64, swizzled granule)
#pragma unroll
      for (int c = 0; c < 4; ++c) {
        float p0 = exp2f(s[c][0] - mrow);
        float p1 = exp2f(s[c][1] - mrow);
        float p2 = exp2f(s[c][2] - mrow);
        float p3 = exp2f(s[c][3] - mrow);
        lrow += (p0 + p1) + (p2 + p3);
        uint2 pk;
        pk.x = pk2b(p0, p1);
        pk.y = pk2b(p2, p3);
        const int gsl = (c * 2 + (lg >> 1)) ^ swz;  // granule (8 shorts)
        *(uint2*)&PsT[w][l15][gsl * 8 + (lg & 1) * 4] = pk;
      }

      // V B-frags + PV
      s16x8 bv[4][2], pa[2];
#pragma unroll
      for (int df = 0; df < 4; ++df)
#pragma unroll
        for (int kh = 0; kh < 2; ++kh)
          bv[df][kh] = *(const s16x8*)&Vs[cur][df * 16 + l15][((kh * 4 + lg) ^ swz) * 8];
#pragma unroll
      for (int kh = 0; kh < 2; ++kh)
        pa[kh] = *(const s16x8*)&PsT[w][l15][(((kh * 4 + lg) ^ swz)) * 8];

      __builtin_amdgcn_s_setprio(1);
#pragma unroll
      for (int kh = 0; kh < 2; ++kh)
#pragma unroll
        for (int df = 0; df < 4; ++df)
          acc[df] = mfma16(pa[kh], bv[df][kh], acc[df]);
      __builtin_amdgcn_s_setprio(0);
    }
    cur ^= 1;
  }

  // epilogue: finish l reduce, transpose-broadcast 1/l, write out
  lrow += __shfl_xor(lrow, 16);
  lrow += __shfl_xor(lrow, 32);
  const float linv = 1.0f / lrow;
  float invT[4];
#pragma unroll
  for (int r = 0; r < 4; ++r)
    invT[r] = __shfl(linv, (lane & 48) + lg * 4 + r);
#pragma unroll
  for (int df = 0; df < 4; ++df)
#pragma unroll
    for (int r = 0; r < 4; ++r) {
      const int qrow = wqbase + lg * 4 + r;
      const int d = df * 16 + l15;
      att[((size_t)(bq * 2048) + qrow) * 1024 + h * 64 + d] =
          f2b(acc[df][r] * invT[r]);
    }
}

// ---------------- launch ----------------
extern "C" void kernel_launch(void* const* d_in, const int* in_sizes, int n_in,
                              void* d_out, int out_size, void* d_ws, size_t ws_size,
                              hipStream_t stream) {
  const float* x  = (const float*)d_in[0];
  const float* wq = (const float*)d_in[1];
  const float* wk = (const float*)d_in[2];
  const float* wv = (const float*)d_in[3];
  const float* wo = (const float*)d_in[4];
  const float* w1 = (const float*)d_in[5];
  const float* w2 = (const float*)d_in[6];
  const float* g1 = (const float*)d_in[7];
  const float* g2 = (const float*)d_in[8];
  float* out = (float*)d_out;

  char* ws = (char*)d_ws;
  const size_t MB = 1u << 20;
  short* wq_b  = (short*)(ws + 0 * MB);
  short* wk_b  = (short*)(ws + 2 * MB);
  short* wv_b  = (short*)(ws + 4 * MB);
  short* wo_b  = (short*)(ws + 6 * MB);
  short* w1_b  = (short*)(ws + 8 * MB);
  short* w2_b  = (short*)(ws + 16 * MB);
  short* xn_b  = (short*)(ws + 24 * MB);
  short* q_b   = (short*)(ws + 32 * MB);
  short* k_b   = (short*)(ws + 40 * MB);
  short* vt_b  = (short*)(ws + 48 * MB);
  short* att_b = (short*)(ws + 56 * MB);
  short* gel_b = (short*)(ws + 32 * MB);  // aliases q/k/vt/att (dead by FFN1)

  // 1. xn = rmsnorm(x, g1)
  rmsnorm_kernel<<<NROWS, 256, 0, stream>>>(x, g1, xn_b);
  // 2. weights -> bf16
  cvt4_kernel<<<2048, 256, 0, stream>>>(wq, wk, wv, wo, wq_b, wk_b, wv_b, wo_b);
  cvt_kernel<<<2048, 256, 0, stream>>>(w1, w1_b, 1 << 22);
  cvt_kernel<<<2048, 256, 0, stream>>>(w2, w2_b, 1 << 22);
  // 3. fused QKV (Q pre-scaled for exp2, V transposed)
  gemm_qkv<<<dim3(24, 32), 256, 0, stream>>>(xn_b, wq_b, wk_b, wv_b, q_b, k_b, vt_b);
  // 4. attention (round-3 grid: bh = x, reversed qb = y)
  attn_kernel<<<dim3(32, 16), 512, 0, stream>>>(q_b, k_b, vt_b, att_b);
  // 5. x1 = x + att @ wo^T  (x1 in d_out, f32)
  gemm_bt<2, 2><<<dim3(8, 64), 256, 0, stream>>>(att_b, wo_b, nullptr, out, x, 1024, 1024, 1024);
  // 6. h = rmsnorm(x1, g2)
  rmsnorm_kernel<<<NROWS, 256, 0, stream>>>(out, g2, xn_b);
  // 7. g = gelu(h @ w1^T)
  gemm_bt<3, 4><<<dim3(32, 32), 256, 0, stream>>>(xn_b, w1_b, gel_b, nullptr, nullptr, 1024, 1024, 4096);
  // 8. out = x1 + g @ w2^T (split-K x2, atomic f32 onto x1)
  gemm_bt<4, 4><<<dim3(8, 32, 2), 256, 0, stream>>>(gel_b, w2_b, nullptr, out, nullptr, 2048, 4096, 1024);
}